// Round 4
// baseline (415.733 us; speedup 1.0000x reference)
//
#include <hip/hip_runtime.h>

#define RES 64
#define CHANNEL 32
#define DIM 512
#define BATCH 32
#define ROWS (RES * RES * CHANNEL)   // 131072

// Kernel 1: scaledT[d*32+b] = L[d] * style[b][d]   (512 x 32 floats = 64 KiB in d_ws)
__global__ void scale_kernel(const float* __restrict__ style,
                             const float* __restrict__ L,
                             float* __restrict__ scaledT) {
    int i = blockIdx.x * 256 + threadIdx.x;   // 0 .. 16383
    int d = i >> 5;
    int b = i & 31;
    scaledT[i] = L[d] * style[b * DIM + d];
}

// Kernel 2: one thread per output row m. acc[b] = sum_d U[m,d]*scaled[d][b]; out[b][m] = acc[b]+mu[m].
// U has no cross-row reuse (streamed once). Sc (scaledT) addresses are wave-uniform and the
// pointer is never written in this kernel -> compiler's uniform-load analysis should emit
// s_load (SMEM/K$ path): zero LDS traffic, zero VMEM issue for Sc, SGPR operand feeds
// v_fmac_f32 directly. No __shared__, no barriers.
__global__ __launch_bounds__(256, 2) void eigen_kernel(
    const float* __restrict__ U,
    const float* __restrict__ mu,
    const float* __restrict__ scaledT,
    float* __restrict__ out) {

    const int tid = threadIdx.x;
    const size_t row = (size_t)blockIdx.x * 256 + tid;
    const float4* __restrict__ u4 = (const float4*)(U + row * DIM);
    const float4* __restrict__ sc4 = (const float4*)scaledT;  // global, uniform indices only

    float acc[BATCH];
#pragma unroll
    for (int b = 0; b < BATCH; ++b) acc[b] = 0.0f;

    // body = 16 d's = 4 float4 per lane = exactly one 64B line per lane.
    // Prefetch next body's line while computing 512 FMAs on the current one.
    float4 cur[4], nxt[4];
#pragma unroll
    for (int p = 0; p < 4; ++p) cur[p] = u4[p];

#pragma unroll 1
    for (int body = 0; body < DIM / 16; ++body) {   // 32 bodies
        if (body + 1 < DIM / 16) {
#pragma unroll
            for (int p = 0; p < 4; ++p) nxt[p] = u4[(body + 1) * 4 + p];
        }
#pragma unroll
        for (int p = 0; p < 4; ++p) {
            const int dbase = body * 16 + p * 4;
#pragma unroll
            for (int j = 0; j < 4; ++j) {
                const float uj = (j == 0) ? cur[p].x : (j == 1) ? cur[p].y
                               : (j == 2) ? cur[p].z : cur[p].w;
                const int sbase = (dbase + j) * 8;   // float4 index of Sc row d
#pragma unroll
                for (int q = 0; q < 8; ++q) {
                    // wave-uniform global load -> expected s_load (SMEM), SGPR operands
                    float4 s = sc4[sbase + q];
                    acc[q * 4 + 0] += uj * s.x;
                    acc[q * 4 + 1] += uj * s.y;
                    acc[q * 4 + 2] += uj * s.z;
                    acc[q * 4 + 3] += uj * s.w;
                }
            }
        }
#pragma unroll
        for (int p = 0; p < 4; ++p) cur[p] = nxt[p];
    }

    const float muv = mu[row];
#pragma unroll
    for (int b = 0; b < BATCH; ++b)
        out[(size_t)b * ROWS + row] = acc[b] + muv;   // per wave: 256B contiguous per b
}

extern "C" void kernel_launch(void* const* d_in, const int* in_sizes, int n_in,
                              void* d_out, int out_size, void* d_ws, size_t ws_size,
                              hipStream_t stream) {
    const float* style = (const float*)d_in[0];   // [32, 512]
    const float* U     = (const float*)d_in[1];   // [64, 64, 32, 512]
    const float* L     = (const float*)d_in[2];   // [512]
    const float* mu    = (const float*)d_in[3];   // [64, 64, 32]
    float* out = (float*)d_out;                   // [32, 64, 64, 32]
    float* scaledT = (float*)d_ws;                // 512*32 floats = 64 KiB

    scale_kernel<<<64, 256, 0, stream>>>(style, L, scaledT);
    eigen_kernel<<<ROWS / 256, 256, 0, stream>>>(U, mu, scaledT, out);
}